// Round 3
// baseline (72.809 us; speedup 1.0000x reference)
//
#include <hip/hip_runtime.h>

// Gaussian splat renderer: B=2, 9 params x 32x32 gaussians -> [B,3,128,128].
//
// REGISTER-RESIDENT single kernel, zero LDS. Evidence from rounds 0/1: any
// scheme that FETCHES gaussian records inside the pixel loop costs ~28us,
// whether fed by s_load (scalar cache thrash) or by LDS broadcast reads
// (wave-uniform ds_read_b128 still occupies the LDS pipe ~12cyc/instr:
// 32 waves/CU x 32 iters x 5 reads x 12cyc = 25.6us -- matches). The VALU
// floor for the math itself is ~5us. So the records now live in VGPRs,
// distributed across lanes: each lane holds 8 gaussian-PAIR records (144
// VGPRs) => each wave carries the full 1024-gaussian set for its batch.
// Each wave sweeps 16 pixels with pure packed-f32 VALU math; the per-pixel
// 4-channel cross-lane sum uses DPP adds (VALU pipe, no LDS, no shuffles).
// Setup (tanh/exp/cov-inverse) is recomputed per wave in the prologue
// (~800 cyc, cheaper than any table round-trip).
//
// 512 blocks x 256 threads = 2048 waves (2/SIMD at ~180 VGPR), 16 px/wave.
// Per-term math is identical to the previously passing kernel.

#define NB   2
#define NG   1024
#define HOUT 128
#define WOUT 128
#define NPW  16              // pixels per wave

typedef float v2f __attribute__((ext_vector_type(2)));

__device__ __forceinline__ float fast_exp(float x) {
    return __builtin_amdgcn_exp2f(x * 1.4426950408889634f);
}
__device__ __forceinline__ float fast_sigmoid(float x) {
    float e = __builtin_amdgcn_exp2f(-x * 1.4426950408889634f);
    return __builtin_amdgcn_rcpf(1.0f + e);
}
__device__ __forceinline__ float fast_tanh(float x) {
    float e = __builtin_amdgcn_exp2f(-x * 2.8853900817779268f);
    return fmaf(2.0f, __builtin_amdgcn_rcpf(1.0f + e), -1.0f);
}

// v += dpp(v); bound_ctrl=true zero-fills invalid lanes, masked-off rows get
// old=0, so the add is a no-op there. All-VALU wave64 reduction.
template<int CTRL, int RM>
__device__ __forceinline__ float dpp_add(float v) {
    int s = __builtin_amdgcn_update_dpp(0, __float_as_int(v), CTRL, RM, 0xF, true);
    return v + __int_as_float(s);
}
// Full 64-lane sum; total lands in lane 63.
__device__ __forceinline__ float wave_sum(float v) {
    v = dpp_add<0x111, 0xF>(v);   // row_shr:1
    v = dpp_add<0x112, 0xF>(v);   // row_shr:2
    v = dpp_add<0x114, 0xF>(v);   // row_shr:4
    v = dpp_add<0x118, 0xF>(v);   // row_shr:8  -> row sums in lanes 15/31/47/63
    v = dpp_add<0x142, 0xA>(v);   // row_bcast15 -> lanes 31,63 = half sums
    v = dpp_add<0x143, 0xC>(v);   // row_bcast31 -> lane 63 = total
    return v;
}

// scalar covariance -> exp2-folded quadratic coefficients (same math as before)
// Returns {A, B2, C} by value (vector elements can't bind to float&).
struct Coefs { float A, B2, C; };
__device__ __forceinline__ Coefs cov_coefs(float p2, float p3, float p4) {
    float ea  = fast_exp(p2);
    float ec  = fast_exp(p4);
    float c00 = ea * ea + 1e-5f;
    float c01 = p3 * ea;
    float c11 = p3 * p3 + ec * ec + 1e-5f;
    float det = c00 * c11 - c01 * c01;
    float id  = 1.0f / det;            // exact divide: det can be ~1e-10
    const float s = -0.72134752044448169f;   // -0.5 * log2(e)
    Coefs r;
    r.A  = s * c11 * id;
    r.B2 = -2.0f * s * c01 * id;
    r.C  = s * c00 * id;
    return r;
}

__global__ __launch_bounds__(256, 2) void gauss_all(const float* __restrict__ params,
                                                    float* __restrict__ out) {
    const int tid  = threadIdx.x;
    const int lane = tid & 63;
    const int wv   = tid >> 6;                  // wave in block [0,4)
    const int blk  = blockIdx.x;
    const int b    = blk >> 8;                  // 256 blocks per batch
    const int pix0 = (((blk & 255) << 2) + wv) * NPW;   // [0,16384)

    // ---- prologue: lane 'lane' computes pair-records pr = lane + 64k ------
    // rec[k]: {mux2, muy2, A2, B22, C2, op2, ocr2, ocg2, ocb2} (v2f = pair)
    v2f rec[8][9];
    const float* P = params + b * 9 * NG;       // channel stride = 1024
    #pragma unroll
    for (int k = 0; k < 8; ++k) {
        const int n0 = 2 * lane + 128 * k;      // even; pair = (n0, n0+1)
        v2f p[9];
        #pragma unroll
        for (int f = 0; f < 9; ++f)
            p[f] = *(const v2f*)(P + f * NG + n0);   // coalesced 8B loads

        // base_grid: -0.96875 + i/16; tanh offset * (2/32)
        const float gw = (float)(n0 & 31);      // even, <=30 -> no row wrap
        const float gh = (float)(n0 >> 5);
        v2f mux2, muy2, A2, B22, C2;
        mux2.x = -0.96875f + gw * 0.0625f + fast_tanh(p[0].x) * 0.0625f;
        mux2.y = -0.96875f + (gw + 1.0f) * 0.0625f + fast_tanh(p[0].y) * 0.0625f;
        muy2.x = -0.96875f + gh * 0.0625f + fast_tanh(p[1].x) * 0.0625f;
        muy2.y = -0.96875f + gh * 0.0625f + fast_tanh(p[1].y) * 0.0625f;
        Coefs cx = cov_coefs(p[2].x, p[3].x, p[4].x);
        Coefs cy = cov_coefs(p[2].y, p[3].y, p[4].y);
        A2.x = cx.A; B22.x = cx.B2; C2.x = cx.C;
        A2.y = cy.A; B22.y = cy.B2; C2.y = cy.C;
        v2f op2, ocr2, ocg2, ocb2;
        op2.x  = fast_sigmoid(p[8].x);         op2.y  = fast_sigmoid(p[8].y);
        ocr2.x = op2.x * fast_sigmoid(p[5].x); ocr2.y = op2.y * fast_sigmoid(p[5].y);
        ocg2.x = op2.x * fast_sigmoid(p[6].x); ocg2.y = op2.y * fast_sigmoid(p[6].y);
        ocb2.x = op2.x * fast_sigmoid(p[7].x); ocb2.y = op2.y * fast_sigmoid(p[7].y);

        rec[k][0] = mux2; rec[k][1] = muy2; rec[k][2] = A2;
        rec[k][3] = B22;  rec[k][4] = C2;   rec[k][5] = op2;
        rec[k][6] = ocr2; rec[k][7] = ocg2; rec[k][8] = ocb2;
    }

    // ---- render: 16 pixels, all 1024 gaussians, zero memory in loop -------
    const int w0 = pix0 & 127;                  // pix0 multiple of 16 -> one row
    const int h0 = pix0 >> 7;
    const float py = -1.0f + (float)h0 * (2.0f / 127.0f);
    const v2f py2 = {py, py};
    float* ob = out + b * 3 * (HOUT * WOUT) + pix0;

    #pragma unroll 2
    for (int i = 0; i < NPW; ++i) {
        const float px = -1.0f + (float)(w0 + i) * (2.0f / 127.0f);
        const v2f px2 = {px, px};
        v2f wsum2 = {0.0f, 0.0f}, ar2 = {0.0f, 0.0f};
        v2f ag2   = {0.0f, 0.0f}, ab2 = {0.0f, 0.0f};

        #pragma unroll
        for (int k = 0; k < 8; ++k) {
            v2f dx = px2 - rec[k][0];
            v2f dy = py2 - rec[k][1];
            v2f m  = rec[k][2] * dx;
            m      = __builtin_elementwise_fma(rec[k][3], dy, m);
            v2f t  = rec[k][4] * dy;
            v2f e2 = __builtin_elementwise_fma(t, dy, m * dx);
            e2 = __builtin_elementwise_max(e2, (v2f){-28.853900817779268f,
                                                     -28.853900817779268f});
            v2f k2 = {__builtin_amdgcn_exp2f(e2.x), __builtin_amdgcn_exp2f(e2.y)};
            wsum2 = __builtin_elementwise_fma(rec[k][5], k2, wsum2);
            ar2   = __builtin_elementwise_fma(rec[k][6], k2, ar2);
            ag2   = __builtin_elementwise_fma(rec[k][7], k2, ag2);
            ab2   = __builtin_elementwise_fma(rec[k][8], k2, ab2);
        }

        float ws = wave_sum(wsum2.x + wsum2.y);
        float rr = wave_sum(ar2.x + ar2.y);
        float gg = wave_sum(ag2.x + ag2.y);
        float bb = wave_sum(ab2.x + ab2.y);

        if (lane == 63) {
            float inv = 1.0f / (ws + 1e-8f);
            ob[i]                   = rr * inv;
            ob[i + HOUT * WOUT]     = gg * inv;
            ob[i + 2 * HOUT * WOUT] = bb * inv;
        }
    }
}

extern "C" void kernel_launch(void* const* d_in, const int* in_sizes, int n_in,
                              void* d_out, int out_size, void* d_ws, size_t ws_size,
                              hipStream_t stream) {
    const float* params = (const float*)d_in[0];
    float* out = (float*)d_out;
    (void)d_ws; (void)ws_size;   // workspace intentionally unused

    // 2 batches * (16384 px / (4 waves * 16 px/wave)) = 2 * 256 = 512 blocks
    hipLaunchKernelGGL(gauss_all, dim3(512), dim3(256), 0, stream, params, out);
}